// Round 9
// baseline (151.672 us; speedup 1.0000x reference)
//
#include <hip/hip_runtime.h>

// Problem constants (match reference)
#define BB 8
#define NN 256
#define FF 64      // F_NODE
#define EE 16      // F_EDGE
#define MM 64      // M_MSG
#define G3 192     // 3*F_NODE
#define OUTD 128
#define ROWS (BB*NN)   // 2048
#define MAXD 64        // padded neighbor cap
#define RB 4           // rows per block (amortizes weight re-reads)

__device__ __forceinline__ float sigmoidf_(float x) {
    return 1.0f / (1.0f + __expf(-x));
}

// ---------------------------------------------------------------------------
// k_prep2: 512 blocks x 512 threads, 4 rows/block.
// Dense coalesced edge scan (8 float4 loads in flight per thread) + per-quad
// LDS-atomic compaction -> gef/nbr/deg. hn0 = nodes @ W_n + b once per node.
// h0 not materialized (pass 0 reads nodes directly).
// ---------------------------------------------------------------------------
__global__ __launch_bounds__(512, 4) void k_prep2(
    const float* __restrict__ nodes, const float* __restrict__ edges,
    const float* __restrict__ Wmsg, const float* __restrict__ bmsg,
    int* __restrict__ deg, int* __restrict__ nbr, float* __restrict__ gef,
    float* __restrict__ hn_out, float* __restrict__ out)
{
    const int r0  = blockIdx.x * RB;
    const int tid = threadIdx.x;
    const int w   = tid >> 6;
    const int lane = tid & 63;

    __shared__ int   sdeg[RB];         // LDS atomic counters
    __shared__ float swm[FF][MM];      // 16 KB: W_msg node part
    __shared__ float part[8][MM];      // 2 KB
    __shared__ float shold[RB][FF];    // staged node feats

    if (blockIdx.x == 0) { out[tid] = 0.0f; out[tid + 512] = 0.0f; }
    if (tid < RB) sdeg[tid] = 0;
    if (tid < RB * FF) {
        int r = tid >> 6;
        shold[r][tid & 63] = nodes[(size_t)(r0 + r) * FF + (tid & 63)];
    }
    __syncthreads();                   // sdeg=0 visible before scan atomics

    // ---- phase 1: all 8 loads + quad-reduces (independent chains) ----
    // Block region: RB rows x 256 edges x 16 floats = 4096 float4s.
    const float4* base4 = (const float4*)(edges + (size_t)r0 * NN * EE);
    float4 v[8];
    bool pred[8];
    #pragma unroll
    for (int it = 0; it < 8; ++it) v[it] = base4[it * 512 + tid];
    #pragma unroll
    for (int it = 0; it < 8; ++it) {
        float s4 = v[it].x + v[it].y + v[it].z + v[it].w;
        s4 += __shfl_xor(s4, 1);
        s4 += __shfl_xor(s4, 2);       // full 16-feat sum in all 4 quad lanes
        pred[it] = (s4 != 0.0f);       // exact: feats non-negative
    }

    // ---- phase 2: per-quad-leader slot assignment + stores ----
    const int q = lane & 3;            // quarter within edge
    #pragma unroll
    for (int it = 0; it < 8; ++it) {
        int e  = it * 128 + (tid >> 2); // edge index 0..1023
        int rr = e >> 8;                // row within block (uniform per it)
        int j  = e & 255;               // neighbor index
        int slot = 0;
        if (pred[it] && q == 0) slot = atomicAdd(&sdeg[rr], 1);
        slot = __shfl(slot, lane & ~3); // broadcast within quad
        if (pred[it] && slot < MAXD) {
            ((float4*)(gef + ((size_t)(r0 + rr) * MAXD + slot) * EE))[q] = v[it];
            if (q == 0) nbr[(r0 + rr) * MAXD + slot] = j;
        }
    }

    // stage W_msg node-part (rows 0..63) into LDS (overlaps other waves' scans)
    for (int i = tid; i < FF * MM; i += 512) swm[i >> 6][i & 63] = Wmsg[i];
    __syncthreads();                   // swm + final sdeg visible

    if (tid < RB) {
        int t = sdeg[tid]; t = t < MAXD ? t : MAXD;
        deg[r0 + tid] = t;
    }

    // ---- hn0 = nodes @ W_n + b_msg (once per node) ----
    // wave w -> row w>>1, k-half w&1 (32 kk each)
    {
        int r = w >> 1, kh = w & 1;
        float p = 0.0f;
        #pragma unroll
        for (int kk = 0; kk < 32; ++kk) {
            int k = kh * 32 + kk;
            p += shold[r][k] * swm[k][lane];
        }
        part[w][lane] = p;
    }
    __syncthreads();
    if (tid < RB * MM) {
        int r = tid >> 6, tt = tid & 63;
        hn_out[(size_t)(r0 + r) * MM + tt] = bmsg[tt]
            + part[2*r][tt] + part[2*r+1][tt];
    }
}

// ---------------------------------------------------------------------------
// k_p12: one message pass, 512 blocks x 512 threads, 4 rows/block.
// Halves per-launch Wi/Wh re-read (50 MB vs 100 MB) and block count vs the
// 2-row version; per-wave FMA density per weight load doubles.
// hsrc = h-state source (nodes for pass 0, h after). Last pass: readout.
// ---------------------------------------------------------------------------
__global__ __launch_bounds__(512, 4) void k_p12(
    const float* __restrict__ Wmsg, const float* __restrict__ bmsg,
    const float* __restrict__ Wi, const float* __restrict__ Wh,
    const float* __restrict__ bi, const float* __restrict__ bh,
    const float* __restrict__ nodes,
    const float* __restrict__ Wg, const float* __restrict__ bg,
    const float* __restrict__ We, const float* __restrict__ be,
    const int* __restrict__ deg, const int* __restrict__ nbr,
    const float* __restrict__ gef, const float* __restrict__ hsrc,
    const float* __restrict__ hn_in, float* __restrict__ hn_out,
    float* __restrict__ h, float* __restrict__ out, int last)
{
    const int r0  = blockIdx.x * RB;
    const int b   = r0 >> 8;           // RB divides 256 -> uniform batch
    const int tid = threadIdx.x;
    const int w   = tid >> 6;
    const int lane = tid & 63;

    __shared__ int   snbr[RB][MAXD];                    // 1 KB
    __shared__ int   sdeg4[RB];
    __shared__ __align__(16) float efeat[RB][MAXD][EE]; // 16 KB
    __shared__ float part[8][MM];                       // 2 KB
    __shared__ float smsg[RB][MM];                      // 1 KB
    __shared__ float shold[RB][FF];                     // 1 KB
    __shared__ float sx[RB][FF];                        // 1 KB
    __shared__ float gI[RB][3][FF], gH[RB][3][FF];      // 6 KB
    __shared__ float shnew[RB][FF];                     // 1 KB
    __shared__ float sg[RB][OUTD], se[RB][OUTD];        // 4 KB

    if (tid < RB) sdeg4[tid] = deg[r0 + tid];

    if (tid < RB * MAXD) {             // 256 threads
        int r = tid >> 6;
        snbr[r][tid & 63] = nbr[(r0 + r) * MAXD + (tid & 63)];
    }
    if (tid < RB * FF) {               // 256 threads
        int r = tid >> 6;
        shold[r][tid & 63] = hsrc[(size_t)(r0 + r) * FF + (tid & 63)];
    }
    if (last && tid >= RB * FF) {      // threads 256..511 -> sx rows 0..3
        int r = (tid >> 6) & 3;
        sx[r][tid & 63] = nodes[(size_t)(r0 + r) * FF + (tid & 63)];
    }
    // compacted edge features: dense float4
    #pragma unroll
    for (int r = 0; r < RB; ++r) {
        int dr = deg[r0 + r];
        const float4* gr = (const float4*)(gef + (size_t)(r0 + r) * MAXD * EE);
        for (int i = tid; i < dr * 4; i += 512) ((float4*)efeat[r])[i] = gr[i];
    }
    float we[EE];
    #pragma unroll
    for (int k = 0; k < EE; ++k) we[k] = Wmsg[(FF + k) * MM + lane];
    __syncthreads();

    // ---- message aggregation: 2 waves per row ----
    {
        int r = w >> 1, sub = w & 1;
        int d = sdeg4[r];
        const float* hb = hn_in + (size_t)b * NN * MM;
        float acc = 0.0f;
        for (int s = sub; s < d; s += 2) {
            int j = snbr[r][s];
            float term = hb[j * MM + lane];
            const float4* e4 = (const float4*)efeat[r][s];
            float4 e0 = e4[0], e1 = e4[1], e2 = e4[2], e3 = e4[3];
            term += e0.x*we[0] + e0.y*we[1] + e0.z*we[2] + e0.w*we[3]
                  + e1.x*we[4] + e1.y*we[5] + e1.z*we[6] + e1.w*we[7]
                  + e2.x*we[8] + e2.y*we[9] + e2.z*we[10] + e2.w*we[11]
                  + e3.x*we[12] + e3.y*we[13] + e3.z*we[14] + e3.w*we[15];
            acc += fmaxf(term, 0.0f);
        }
        part[w][lane] = acc;
    }
    __syncthreads();
    if ((w & 1) == 0) {
        int r = w >> 1;
        smsg[r][lane] = part[w][lane] + part[w + 1][lane];
    }
    __syncthreads();

    // ---- GRU gates: waves 0-2 -> gi gate w (all 4 rows); 3-5 -> gh ----
    if (w < 3) {
        float a0 = bi[w * FF + lane];
        float a1 = a0, a2 = a0, a3 = a0;
        #pragma unroll 4
        for (int k = 0; k < FF; ++k) {
            float wgt = Wi[k * G3 + w * FF + lane];
            a0 += smsg[0][k] * wgt;
            a1 += smsg[1][k] * wgt;
            a2 += smsg[2][k] * wgt;
            a3 += smsg[3][k] * wgt;
        }
        gI[0][w][lane] = a0; gI[1][w][lane] = a1;
        gI[2][w][lane] = a2; gI[3][w][lane] = a3;
    } else if (w < 6) {
        int g = w - 3;
        float a0 = bh[g * FF + lane];
        float a1 = a0, a2 = a0, a3 = a0;
        #pragma unroll 4
        for (int k = 0; k < FF; ++k) {
            float wgt = Wh[k * G3 + g * FF + lane];
            a0 += shold[0][k] * wgt;
            a1 += shold[1][k] * wgt;
            a2 += shold[2][k] * wgt;
            a3 += shold[3][k] * wgt;
        }
        gH[0][g][lane] = a0; gH[1][g][lane] = a1;
        gH[2][g][lane] = a2; gH[3][g][lane] = a3;
    }
    __syncthreads();

    // ---- combine: 256 threads = 4 rows x 64 features ----
    if (tid < RB * FF) {
        int r = tid >> 6, tt = tid & 63;
        float rr = sigmoidf_(gI[r][0][tt] + gH[r][0][tt]);
        float zz = sigmoidf_(gI[r][1][tt] + gH[r][1][tt]);
        float ng = tanhf(gI[r][2][tt] + rr * gH[r][2][tt]);
        float hold = shold[r][tt];
        float hnew = (1.0f - zz) * ng + zz * hold;
        if (sdeg4[r] == 0) hnew = hold;
        shnew[r][tt] = hnew;
        if (!last) h[(size_t)(r0 + r) * FF + tt] = hnew;
    }
    __syncthreads();

    if (!last) {
        // hn for next pass: wave w -> row w>>1, k-half w&1
        {
            int r = w >> 1, kh = w & 1;
            float p = 0.0f;
            #pragma unroll
            for (int kk = 0; kk < 32; ++kk) {
                int k = kh * 32 + kk;
                p += shnew[r][k] * Wmsg[k * MM + lane];
            }
            part[w][lane] = p;
        }
        __syncthreads();
        if (tid < RB * MM) {
            int r = tid >> 6, tt = tid & 63;
            hn_out[(size_t)(r0 + r) * MM + tt] = bmsg[tt]
                + part[2*r][tt] + part[2*r+1][tt];
        }
    } else {
        // gated readout: 4 groups of 128 thr = (row-base, gate-vs-emb); 2 rows each
        int grp = tid >> 7, o = tid & 127;
        int kind = grp & 1, rbase = grp >> 1;
        #pragma unroll
        for (int t = 0; t < 2; ++t) {
            int r = rbase + 2 * t;
            if (kind == 0) {
                float g = bg[o];
                #pragma unroll 4
                for (int k = 0; k < FF; ++k) g += shnew[r][k] * Wg[k * OUTD + o];
                #pragma unroll 4
                for (int k = 0; k < FF; ++k) g += sx[r][k] * Wg[(FF + k) * OUTD + o];
                sg[r][o] = g;
            } else {
                float e = be[o];
                #pragma unroll 4
                for (int k = 0; k < FF; ++k) e += shnew[r][k] * We[k * OUTD + o];
                se[r][o] = e;
            }
        }
        __syncthreads();
        if (tid < OUTD) {
            float v = 0.0f;
            #pragma unroll
            for (int r = 0; r < RB; ++r)
                if (sdeg4[r] != 0) v += sigmoidf_(sg[r][tid]) * se[r][tid];
            atomicAdd(&out[b * OUTD + tid], v);
        }
    }
}

// ---------------------------------------------------------------------------
extern "C" void kernel_launch(void* const* d_in, const int* in_sizes, int n_in,
                              void* d_out, int out_size, void* d_ws, size_t ws_size,
                              hipStream_t stream) {
    const float* nodes = (const float*)d_in[0];
    const float* edges = (const float*)d_in[1];
    const float* Wmsg  = (const float*)d_in[2];
    const float* bmsg  = (const float*)d_in[3];
    const float* Wi    = (const float*)d_in[4];
    const float* Wh    = (const float*)d_in[5];
    const float* bi    = (const float*)d_in[6];
    const float* bh    = (const float*)d_in[7];
    const float* Wg    = (const float*)d_in[8];
    const float* bg    = (const float*)d_in[9];
    const float* We    = (const float*)d_in[10];
    const float* be    = (const float*)d_in[11];
    float* out = (float*)d_out;
    char* ws = (char*)d_ws;

    int*   deg  = (int*)ws;                                        // 8 KB
    int*   nbr  = (int*)(ws + 8192);                               // 512 KB
    float* gef  = (float*)(ws + 8192 + (size_t)ROWS * MAXD * 4);   // 8 MB
    float* h    = gef + (size_t)ROWS * MAXD * EE;
    float* hnA  = h   + (size_t)ROWS * FF;
    float* hnB  = hnA + (size_t)ROWS * MM;

    // launch 1: prep (dense scan + compaction + hn0; h0 not materialized)
    k_prep2<<<ROWS/RB, 512, 0, stream>>>(nodes, edges, Wmsg, bmsg,
                                         deg, nbr, gef, hnA, out);
    // launch 2: pass 0  (h-state from nodes; hnA -> hnB)
    k_p12<<<ROWS/RB, 512, 0, stream>>>(Wmsg, bmsg, Wi, Wh, bi, bh,
                                       nodes, Wg, bg, We, be, deg, nbr, gef,
                                       nodes, hnA, hnB, h, out, 0);
    // launch 3: pass 1  (h-state from h; hnB -> hnA)
    k_p12<<<ROWS/RB, 512, 0, stream>>>(Wmsg, bmsg, Wi, Wh, bi, bh,
                                       nodes, Wg, bg, We, be, deg, nbr, gef,
                                       h, hnB, hnA, h, out, 0);
    // launch 4: pass 2 + readout (h-state from h; hnA -> unused)
    k_p12<<<ROWS/RB, 512, 0, stream>>>(Wmsg, bmsg, Wi, Wh, bi, bh,
                                       nodes, Wg, bg, We, be, deg, nbr, gef,
                                       h, hnA, hnB, h, out, 1);
}

// Round 10
// 150.197 us; speedup vs baseline: 1.0098x; 1.0098x over previous
//
#include <hip/hip_runtime.h>

// Problem constants (match reference)
#define BB 8
#define NN 256
#define FF 64      // F_NODE
#define EE 16      // F_EDGE
#define MM 64      // M_MSG
#define G3 192     // 3*F_NODE
#define OUTD 128
#define ROWS (BB*NN)   // 2048
#define MAXD 64        // padded neighbor cap

typedef float f4_ __attribute__((ext_vector_type(4)));

__device__ __forceinline__ float sigmoidf_(float x) {
    return 1.0f / (1.0f + __expf(-x));
}

// ---------------------------------------------------------------------------
// k_prep2: 1024 blocks x 512 threads, 2 rows/block (RB=2 verified best).
// Dense coalesced edge scan with NONTEMPORAL loads: edges are read exactly
// once, and the preceding 256 MiB ws poison fill leaves L3 fully dirty —
// normal loads force a dirty-victim writeback per allocated line. `nt`
// avoids L3 allocation entirely. Per-quad LDS-atomic compaction -> gef/nbr/
// deg. hn0 = nodes @ W_n + b once per node. h0 not materialized.
// ---------------------------------------------------------------------------
__global__ __launch_bounds__(512, 4) void k_prep2(
    const float* __restrict__ nodes, const float* __restrict__ edges,
    const float* __restrict__ Wmsg, const float* __restrict__ bmsg,
    int* __restrict__ deg, int* __restrict__ nbr, float* __restrict__ gef,
    float* __restrict__ hn_out, float* __restrict__ out)
{
    const int r0  = blockIdx.x * 2;
    const int tid = threadIdx.x;
    const int w   = tid >> 6;
    const int lane = tid & 63;

    __shared__ int   sdeg[2];          // LDS atomic counters
    __shared__ float swm[FF][MM];      // 16 KB: W_msg node part
    __shared__ float part[8][MM];      // 2 KB
    __shared__ float shold[2][FF];     // staged node feats

    if (blockIdx.x == 0) { out[tid] = 0.0f; out[tid + 512] = 0.0f; }
    if (tid < 2) sdeg[tid] = 0;
    if (tid < 2 * FF) {
        int r = tid >> 6;
        shold[r][tid & 63] = nodes[(size_t)(r0 + r) * FF + (tid & 63)];
    }
    __syncthreads();                   // sdeg=0 visible before scan atomics

    // ---- phase 1: all 4 loads (nontemporal) + quad-reduces ----
    const f4_* base4 = (const f4_*)(edges + (size_t)r0 * NN * EE);
    f4_ v[4];
    bool pred[4];
    #pragma unroll
    for (int it = 0; it < 4; ++it)
        v[it] = __builtin_nontemporal_load(&base4[it * 512 + tid]);
    #pragma unroll
    for (int it = 0; it < 4; ++it) {
        float s4 = v[it].x + v[it].y + v[it].z + v[it].w;
        s4 += __shfl_xor(s4, 1);
        s4 += __shfl_xor(s4, 2);       // full 16-feat sum in all 4 quad lanes
        pred[it] = (s4 != 0.0f);       // exact: feats non-negative
    }

    // ---- phase 2: per-quad-leader slot assignment + stores ----
    const int q = lane & 3;            // quarter within edge
    #pragma unroll
    for (int it = 0; it < 4; ++it) {
        int e  = it * 128 + (tid >> 2); // edge index 0..511
        int rr = e >> 8;                // row within block (uniform per it)
        int j  = e & 255;               // neighbor index
        int slot = 0;
        if (pred[it] && q == 0) slot = atomicAdd(&sdeg[rr], 1);
        slot = __shfl(slot, lane & ~3); // broadcast within quad
        if (pred[it] && slot < MAXD) {
            ((f4_*)(gef + ((size_t)(r0 + rr) * MAXD + slot) * EE))[q] = v[it];
            if (q == 0) nbr[(r0 + rr) * MAXD + slot] = j;
        }
    }

    // stage W_msg node-part (rows 0..63) into LDS (overlaps other waves' scans)
    for (int i = tid; i < FF * MM; i += 512) swm[i >> 6][i & 63] = Wmsg[i];
    __syncthreads();                   // swm + final sdeg visible

    if (tid < 2) {
        int t = sdeg[tid]; t = t < MAXD ? t : MAXD;
        deg[r0 + tid] = t;
    }

    // ---- hn0 = nodes @ W_n + b_msg (once per node) ----
    {
        int r = w >> 2, kq = w & 3;
        float p = 0.0f;
        #pragma unroll
        for (int kk = 0; kk < 16; ++kk) {
            int k = kq * 16 + kk;
            p += shold[r][k] * swm[k][lane];
        }
        part[w][lane] = p;
    }
    __syncthreads();
    if (tid < 2 * MM) {
        int r = tid >> 6, tt = tid & 63;
        hn_out[(size_t)(r0 + r) * MM + tt] = bmsg[tt]
            + part[r*4+0][tt] + part[r*4+1][tt] + part[r*4+2][tt] + part[r*4+3][tt];
    }
}

// ---------------------------------------------------------------------------
// k_p12: one message pass (verified round-7 version, unchanged). hsrc =
// h-state source (nodes for pass 0, h after). Last pass: gated readout.
// ---------------------------------------------------------------------------
__global__ __launch_bounds__(512, 4) void k_p12(
    const float* __restrict__ Wmsg, const float* __restrict__ bmsg,
    const float* __restrict__ Wi, const float* __restrict__ Wh,
    const float* __restrict__ bi, const float* __restrict__ bh,
    const float* __restrict__ nodes,
    const float* __restrict__ Wg, const float* __restrict__ bg,
    const float* __restrict__ We, const float* __restrict__ be,
    const int* __restrict__ deg, const int* __restrict__ nbr,
    const float* __restrict__ gef, const float* __restrict__ hsrc,
    const float* __restrict__ hn_in, float* __restrict__ hn_out,
    float* __restrict__ h, float* __restrict__ out, int last)
{
    const int r0  = blockIdx.x * 2;
    const int b   = r0 >> 8;
    const int tid = threadIdx.x;
    const int w   = tid >> 6;
    const int lane = tid & 63;

    __shared__ int   snbr[2][MAXD];
    __shared__ int   sdeg[2];
    __shared__ __align__(16) float efeat[2][MAXD][EE];
    __shared__ float part[8][MM];
    __shared__ float smsg[2][MM];
    __shared__ float shold[2][FF];
    __shared__ float sx[2][FF];
    __shared__ float gI[2][3][FF], gH[2][3][FF];
    __shared__ float shnew[2][FF];
    __shared__ float sg[2][OUTD], se[2][OUTD];

    const int d0 = deg[r0], d1 = deg[r0 + 1];
    if (tid == 0) { sdeg[0] = d0; sdeg[1] = d1; }

    if (tid < 2 * MAXD) {
        int r = tid >> 6;
        snbr[r][tid & 63] = nbr[(r0 + r) * MAXD + (tid & 63)];
    }
    if (tid < 2 * FF) {
        int r = tid >> 6;
        shold[r][tid & 63] = hsrc[(size_t)(r0 + r) * FF + (tid & 63)];
    }
    if (last && tid >= 2 * FF && tid < 4 * FF) {
        int r = (tid >> 6) & 1;
        sx[r][tid & 63] = nodes[(size_t)(r0 + r) * FF + (tid & 63)];
    }
    {
        const float4* g0 = (const float4*)(gef + (size_t)r0 * MAXD * EE);
        const float4* g1 = (const float4*)(gef + (size_t)(r0 + 1) * MAXD * EE);
        for (int i = tid; i < d0 * 4; i += 512) ((float4*)efeat[0])[i] = g0[i];
        for (int i = tid; i < d1 * 4; i += 512) ((float4*)efeat[1])[i] = g1[i];
    }
    float we[EE];
    #pragma unroll
    for (int k = 0; k < EE; ++k) we[k] = Wmsg[(FF + k) * MM + lane];
    __syncthreads();

    // ---- message aggregation: 4 waves per row ----
    {
        int r = w >> 2, sub = w & 3;
        int d = sdeg[r];
        const float* hb = hn_in + (size_t)b * NN * MM;
        float acc = 0.0f;
        for (int s = sub; s < d; s += 4) {
            int j = snbr[r][s];
            float term = hb[j * MM + lane];
            const float4* e4 = (const float4*)efeat[r][s];
            float4 e0 = e4[0], e1 = e4[1], e2 = e4[2], e3 = e4[3];
            term += e0.x*we[0] + e0.y*we[1] + e0.z*we[2] + e0.w*we[3]
                  + e1.x*we[4] + e1.y*we[5] + e1.z*we[6] + e1.w*we[7]
                  + e2.x*we[8] + e2.y*we[9] + e2.z*we[10] + e2.w*we[11]
                  + e3.x*we[12] + e3.y*we[13] + e3.z*we[14] + e3.w*we[15];
            acc += fmaxf(term, 0.0f);
        }
        part[w][lane] = acc;
    }
    __syncthreads();
    if ((w & 3) == 0) {
        int r = w >> 2;
        smsg[r][lane] = part[w][lane] + part[w + 1][lane]
                      + part[w + 2][lane] + part[w + 3][lane];
    }
    __syncthreads();

    // ---- GRU gates ----
    if (w < 3) {
        float a0 = bi[w * FF + lane], a1 = a0;
        #pragma unroll 4
        for (int k = 0; k < FF; ++k) {
            float wgt = Wi[k * G3 + w * FF + lane];
            a0 += smsg[0][k] * wgt;
            a1 += smsg[1][k] * wgt;
        }
        gI[0][w][lane] = a0; gI[1][w][lane] = a1;
    } else if (w < 6) {
        int g = w - 3;
        float a0 = bh[g * FF + lane], a1 = a0;
        #pragma unroll 4
        for (int k = 0; k < FF; ++k) {
            float wgt = Wh[k * G3 + g * FF + lane];
            a0 += shold[0][k] * wgt;
            a1 += shold[1][k] * wgt;
        }
        gH[0][g][lane] = a0; gH[1][g][lane] = a1;
    }
    __syncthreads();

    // ---- combine ----
    if (tid < 2 * FF) {
        int r = tid >> 6, tt = tid & 63;
        float rr = sigmoidf_(gI[r][0][tt] + gH[r][0][tt]);
        float zz = sigmoidf_(gI[r][1][tt] + gH[r][1][tt]);
        float ng = tanhf(gI[r][2][tt] + rr * gH[r][2][tt]);
        float hold = shold[r][tt];
        float hnew = (1.0f - zz) * ng + zz * hold;
        if (sdeg[r] == 0) hnew = hold;
        shnew[r][tt] = hnew;
        if (!last) h[(size_t)(r0 + r) * FF + tt] = hnew;
    }
    __syncthreads();

    if (!last) {
        {
            int r = w >> 2, kq = w & 3;
            float p = 0.0f;
            #pragma unroll
            for (int kk = 0; kk < 16; ++kk) {
                int k = kq * 16 + kk;
                p += shnew[r][k] * Wmsg[k * MM + lane];
            }
            part[w][lane] = p;
        }
        __syncthreads();
        if (tid < 2 * MM) {
            int r = tid >> 6, tt = tid & 63;
            hn_out[(size_t)(r0 + r) * MM + tt] = bmsg[tt]
                + part[r*4+0][tt] + part[r*4+1][tt] + part[r*4+2][tt] + part[r*4+3][tt];
        }
    } else {
        int grp = tid >> 7, o = tid & 127;
        int r = grp >> 1, kind = grp & 1;
        if (kind == 0) {
            float g = bg[o];
            #pragma unroll 4
            for (int k = 0; k < FF; ++k) g += shnew[r][k] * Wg[k * OUTD + o];
            #pragma unroll 4
            for (int k = 0; k < FF; ++k) g += sx[r][k] * Wg[(FF + k) * OUTD + o];
            sg[r][o] = g;
        } else {
            float e = be[o];
            #pragma unroll 4
            for (int k = 0; k < FF; ++k) e += shnew[r][k] * We[k * OUTD + o];
            se[r][o] = e;
        }
        __syncthreads();
        if (tid < OUTD) {
            float v0 = (sdeg[0] != 0) ? sigmoidf_(sg[0][tid]) * se[0][tid] : 0.0f;
            float v1 = (sdeg[1] != 0) ? sigmoidf_(sg[1][tid]) * se[1][tid] : 0.0f;
            atomicAdd(&out[b * OUTD + tid], v0 + v1);
        }
    }
}

// ---------------------------------------------------------------------------
extern "C" void kernel_launch(void* const* d_in, const int* in_sizes, int n_in,
                              void* d_out, int out_size, void* d_ws, size_t ws_size,
                              hipStream_t stream) {
    const float* nodes = (const float*)d_in[0];
    const float* edges = (const float*)d_in[1];
    const float* Wmsg  = (const float*)d_in[2];
    const float* bmsg  = (const float*)d_in[3];
    const float* Wi    = (const float*)d_in[4];
    const float* Wh    = (const float*)d_in[5];
    const float* bi    = (const float*)d_in[6];
    const float* bh    = (const float*)d_in[7];
    const float* Wg    = (const float*)d_in[8];
    const float* bg    = (const float*)d_in[9];
    const float* We    = (const float*)d_in[10];
    const float* be    = (const float*)d_in[11];
    float* out = (float*)d_out;
    char* ws = (char*)d_ws;

    int*   deg  = (int*)ws;                                        // 8 KB
    int*   nbr  = (int*)(ws + 8192);                               // 512 KB
    float* gef  = (float*)(ws + 8192 + (size_t)ROWS * MAXD * 4);   // 8 MB
    float* h    = gef + (size_t)ROWS * MAXD * EE;
    float* hnA  = h   + (size_t)ROWS * FF;
    float* hnB  = hnA + (size_t)ROWS * MM;

    // launch 1: prep (NT dense scan + compaction + hn0)
    k_prep2<<<ROWS/2, 512, 0, stream>>>(nodes, edges, Wmsg, bmsg,
                                        deg, nbr, gef, hnA, out);
    // launch 2: pass 0  (h-state from nodes; hnA -> hnB)
    k_p12<<<ROWS/2, 512, 0, stream>>>(Wmsg, bmsg, Wi, Wh, bi, bh,
                                      nodes, Wg, bg, We, be, deg, nbr, gef,
                                      nodes, hnA, hnB, h, out, 0);
    // launch 3: pass 1  (h-state from h; hnB -> hnA)
    k_p12<<<ROWS/2, 512, 0, stream>>>(Wmsg, bmsg, Wi, Wh, bi, bh,
                                      nodes, Wg, bg, We, be, deg, nbr, gef,
                                      h, hnB, hnA, h, out, 0);
    // launch 4: pass 2 + readout (h-state from h)
    k_p12<<<ROWS/2, 512, 0, stream>>>(Wmsg, bmsg, Wi, Wh, bi, bh,
                                      nodes, Wg, bg, We, be, deg, nbr, gef,
                                      h, hnA, hnB, h, out, 1);
}

// Round 11
// 145.299 us; speedup vs baseline: 1.0439x; 1.0337x over previous
//
#include <hip/hip_runtime.h>

// Problem constants (match reference)
#define BB 8
#define NN 256
#define FF 64      // F_NODE
#define EE 16      // F_EDGE
#define MM 64      // M_MSG
#define G3 192     // 3*F_NODE
#define OUTD 128
#define ROWS (BB*NN)   // 2048
#define MAXD 64        // padded neighbor cap

__device__ __forceinline__ float sigmoidf_(float x) {
    return 1.0f / (1.0f + __expf(-x));
}

// ---------------------------------------------------------------------------
// k_prep2: 1024 blocks x 512 threads, 2 rows/block (verified session best).
// Dense coalesced edge scan (lane i reads float4 #i of the block's contiguous
// 32 KB edge region) + per-quad LDS-atomic compaction -> gef/nbr/deg.
// hn0 = nodes @ W_n + b once per node. h0 not materialized (pass 0 reads
// nodes directly).
// Ledger on this kernel's ~20 us: spill-fix via (512,4) was the one real
// lever (-98 us); coalescing rewrite, chain surgery, RB=4, NT loads all
// null-to-negative. Residual is dispatch-ramp + cold-memory structural.
// ---------------------------------------------------------------------------
__global__ __launch_bounds__(512, 4) void k_prep2(
    const float* __restrict__ nodes, const float* __restrict__ edges,
    const float* __restrict__ Wmsg, const float* __restrict__ bmsg,
    int* __restrict__ deg, int* __restrict__ nbr, float* __restrict__ gef,
    float* __restrict__ hn_out, float* __restrict__ out)
{
    const int r0  = blockIdx.x * 2;
    const int tid = threadIdx.x;
    const int w   = tid >> 6;
    const int lane = tid & 63;

    __shared__ int   sdeg[2];          // LDS atomic counters
    __shared__ float swm[FF][MM];      // 16 KB: W_msg node part
    __shared__ float part[8][MM];      // 2 KB
    __shared__ float shold[2][FF];     // staged node feats

    if (blockIdx.x == 0) { out[tid] = 0.0f; out[tid + 512] = 0.0f; }
    if (tid < 2) sdeg[tid] = 0;
    if (tid < 2 * FF) {
        int r = tid >> 6;
        shold[r][tid & 63] = nodes[(size_t)(r0 + r) * FF + (tid & 63)];
    }
    __syncthreads();                   // sdeg=0 visible before scan atomics

    // ---- phase 1: all 4 loads + quad-reduces (independent chains) ----
    const float4* base4 = (const float4*)(edges + (size_t)r0 * NN * EE);
    float4 v[4];
    bool pred[4];
    #pragma unroll
    for (int it = 0; it < 4; ++it) v[it] = base4[it * 512 + tid];
    #pragma unroll
    for (int it = 0; it < 4; ++it) {
        float s4 = v[it].x + v[it].y + v[it].z + v[it].w;
        s4 += __shfl_xor(s4, 1);
        s4 += __shfl_xor(s4, 2);       // full 16-feat sum in all 4 quad lanes
        pred[it] = (s4 != 0.0f);       // exact: feats non-negative
    }

    // ---- phase 2: per-quad-leader slot assignment + stores ----
    const int q = lane & 3;            // quarter within edge
    #pragma unroll
    for (int it = 0; it < 4; ++it) {
        int e  = it * 128 + (tid >> 2); // edge index 0..511
        int rr = e >> 8;                // row within block (uniform per it)
        int j  = e & 255;               // neighbor index
        int slot = 0;
        if (pred[it] && q == 0) slot = atomicAdd(&sdeg[rr], 1);
        slot = __shfl(slot, lane & ~3); // broadcast within quad
        if (pred[it] && slot < MAXD) {
            ((float4*)(gef + ((size_t)(r0 + rr) * MAXD + slot) * EE))[q] = v[it];
            if (q == 0) nbr[(r0 + rr) * MAXD + slot] = j;
        }
    }

    // stage W_msg node-part (rows 0..63) into LDS (overlaps other waves' scans)
    for (int i = tid; i < FF * MM; i += 512) swm[i >> 6][i & 63] = Wmsg[i];
    __syncthreads();                   // swm + final sdeg visible

    if (tid < 2) {
        int t = sdeg[tid]; t = t < MAXD ? t : MAXD;
        deg[r0 + tid] = t;
    }

    // ---- hn0 = nodes @ W_n + b_msg (once per node) ----
    {
        int r = w >> 2, kq = w & 3;
        float p = 0.0f;
        #pragma unroll
        for (int kk = 0; kk < 16; ++kk) {
            int k = kq * 16 + kk;
            p += shold[r][k] * swm[k][lane];
        }
        part[w][lane] = p;
    }
    __syncthreads();
    if (tid < 2 * MM) {
        int r = tid >> 6, tt = tid & 63;
        hn_out[(size_t)(r0 + r) * MM + tt] = bmsg[tt]
            + part[r*4+0][tt] + part[r*4+1][tt] + part[r*4+2][tt] + part[r*4+3][tt];
    }
}

// ---------------------------------------------------------------------------
// k_p12: one message pass (verified round-7 version). hsrc = h-state source
// (nodes for pass 0, h after). Last pass: gated readout + atomics.
// ---------------------------------------------------------------------------
__global__ __launch_bounds__(512, 4) void k_p12(
    const float* __restrict__ Wmsg, const float* __restrict__ bmsg,
    const float* __restrict__ Wi, const float* __restrict__ Wh,
    const float* __restrict__ bi, const float* __restrict__ bh,
    const float* __restrict__ nodes,
    const float* __restrict__ Wg, const float* __restrict__ bg,
    const float* __restrict__ We, const float* __restrict__ be,
    const int* __restrict__ deg, const int* __restrict__ nbr,
    const float* __restrict__ gef, const float* __restrict__ hsrc,
    const float* __restrict__ hn_in, float* __restrict__ hn_out,
    float* __restrict__ h, float* __restrict__ out, int last)
{
    const int r0  = blockIdx.x * 2;
    const int b   = r0 >> 8;
    const int tid = threadIdx.x;
    const int w   = tid >> 6;
    const int lane = tid & 63;

    __shared__ int   snbr[2][MAXD];
    __shared__ int   sdeg[2];
    __shared__ __align__(16) float efeat[2][MAXD][EE];
    __shared__ float part[8][MM];
    __shared__ float smsg[2][MM];
    __shared__ float shold[2][FF];
    __shared__ float sx[2][FF];
    __shared__ float gI[2][3][FF], gH[2][3][FF];
    __shared__ float shnew[2][FF];
    __shared__ float sg[2][OUTD], se[2][OUTD];

    const int d0 = deg[r0], d1 = deg[r0 + 1];
    if (tid == 0) { sdeg[0] = d0; sdeg[1] = d1; }

    if (tid < 2 * MAXD) {
        int r = tid >> 6;
        snbr[r][tid & 63] = nbr[(r0 + r) * MAXD + (tid & 63)];
    }
    if (tid < 2 * FF) {
        int r = tid >> 6;
        shold[r][tid & 63] = hsrc[(size_t)(r0 + r) * FF + (tid & 63)];
    }
    if (last && tid >= 2 * FF && tid < 4 * FF) {
        int r = (tid >> 6) & 1;
        sx[r][tid & 63] = nodes[(size_t)(r0 + r) * FF + (tid & 63)];
    }
    {
        const float4* g0 = (const float4*)(gef + (size_t)r0 * MAXD * EE);
        const float4* g1 = (const float4*)(gef + (size_t)(r0 + 1) * MAXD * EE);
        for (int i = tid; i < d0 * 4; i += 512) ((float4*)efeat[0])[i] = g0[i];
        for (int i = tid; i < d1 * 4; i += 512) ((float4*)efeat[1])[i] = g1[i];
    }
    float we[EE];
    #pragma unroll
    for (int k = 0; k < EE; ++k) we[k] = Wmsg[(FF + k) * MM + lane];
    __syncthreads();

    // ---- message aggregation: 4 waves per row ----
    {
        int r = w >> 2, sub = w & 3;
        int d = sdeg[r];
        const float* hb = hn_in + (size_t)b * NN * MM;
        float acc = 0.0f;
        for (int s = sub; s < d; s += 4) {
            int j = snbr[r][s];
            float term = hb[j * MM + lane];
            const float4* e4 = (const float4*)efeat[r][s];
            float4 e0 = e4[0], e1 = e4[1], e2 = e4[2], e3 = e4[3];
            term += e0.x*we[0] + e0.y*we[1] + e0.z*we[2] + e0.w*we[3]
                  + e1.x*we[4] + e1.y*we[5] + e1.z*we[6] + e1.w*we[7]
                  + e2.x*we[8] + e2.y*we[9] + e2.z*we[10] + e2.w*we[11]
                  + e3.x*we[12] + e3.y*we[13] + e3.z*we[14] + e3.w*we[15];
            acc += fmaxf(term, 0.0f);
        }
        part[w][lane] = acc;
    }
    __syncthreads();
    if ((w & 3) == 0) {
        int r = w >> 2;
        smsg[r][lane] = part[w][lane] + part[w + 1][lane]
                      + part[w + 2][lane] + part[w + 3][lane];
    }
    __syncthreads();

    // ---- GRU gates ----
    if (w < 3) {
        float a0 = bi[w * FF + lane], a1 = a0;
        #pragma unroll 4
        for (int k = 0; k < FF; ++k) {
            float wgt = Wi[k * G3 + w * FF + lane];
            a0 += smsg[0][k] * wgt;
            a1 += smsg[1][k] * wgt;
        }
        gI[0][w][lane] = a0; gI[1][w][lane] = a1;
    } else if (w < 6) {
        int g = w - 3;
        float a0 = bh[g * FF + lane], a1 = a0;
        #pragma unroll 4
        for (int k = 0; k < FF; ++k) {
            float wgt = Wh[k * G3 + g * FF + lane];
            a0 += shold[0][k] * wgt;
            a1 += shold[1][k] * wgt;
        }
        gH[0][g][lane] = a0; gH[1][g][lane] = a1;
    }
    __syncthreads();

    // ---- combine ----
    if (tid < 2 * FF) {
        int r = tid >> 6, tt = tid & 63;
        float rr = sigmoidf_(gI[r][0][tt] + gH[r][0][tt]);
        float zz = sigmoidf_(gI[r][1][tt] + gH[r][1][tt]);
        float ng = tanhf(gI[r][2][tt] + rr * gH[r][2][tt]);
        float hold = shold[r][tt];
        float hnew = (1.0f - zz) * ng + zz * hold;
        if (sdeg[r] == 0) hnew = hold;
        shnew[r][tt] = hnew;
        if (!last) h[(size_t)(r0 + r) * FF + tt] = hnew;
    }
    __syncthreads();

    if (!last) {
        {
            int r = w >> 2, kq = w & 3;
            float p = 0.0f;
            #pragma unroll
            for (int kk = 0; kk < 16; ++kk) {
                int k = kq * 16 + kk;
                p += shnew[r][k] * Wmsg[k * MM + lane];
            }
            part[w][lane] = p;
        }
        __syncthreads();
        if (tid < 2 * MM) {
            int r = tid >> 6, tt = tid & 63;
            hn_out[(size_t)(r0 + r) * MM + tt] = bmsg[tt]
                + part[r*4+0][tt] + part[r*4+1][tt] + part[r*4+2][tt] + part[r*4+3][tt];
        }
    } else {
        int grp = tid >> 7, o = tid & 127;
        int r = grp >> 1, kind = grp & 1;
        if (kind == 0) {
            float g = bg[o];
            #pragma unroll 4
            for (int k = 0; k < FF; ++k) g += shnew[r][k] * Wg[k * OUTD + o];
            #pragma unroll 4
            for (int k = 0; k < FF; ++k) g += sx[r][k] * Wg[(FF + k) * OUTD + o];
            sg[r][o] = g;
        } else {
            float e = be[o];
            #pragma unroll 4
            for (int k = 0; k < FF; ++k) e += shnew[r][k] * We[k * OUTD + o];
            se[r][o] = e;
        }
        __syncthreads();
        if (tid < OUTD) {
            float v0 = (sdeg[0] != 0) ? sigmoidf_(sg[0][tid]) * se[0][tid] : 0.0f;
            float v1 = (sdeg[1] != 0) ? sigmoidf_(sg[1][tid]) * se[1][tid] : 0.0f;
            atomicAdd(&out[b * OUTD + tid], v0 + v1);
        }
    }
}

// ---------------------------------------------------------------------------
extern "C" void kernel_launch(void* const* d_in, const int* in_sizes, int n_in,
                              void* d_out, int out_size, void* d_ws, size_t ws_size,
                              hipStream_t stream) {
    const float* nodes = (const float*)d_in[0];
    const float* edges = (const float*)d_in[1];
    const float* Wmsg  = (const float*)d_in[2];
    const float* bmsg  = (const float*)d_in[3];
    const float* Wi    = (const float*)d_in[4];
    const float* Wh    = (const float*)d_in[5];
    const float* bi    = (const float*)d_in[6];
    const float* bh    = (const float*)d_in[7];
    const float* Wg    = (const float*)d_in[8];
    const float* bg    = (const float*)d_in[9];
    const float* We    = (const float*)d_in[10];
    const float* be    = (const float*)d_in[11];
    float* out = (float*)d_out;
    char* ws = (char*)d_ws;

    int*   deg  = (int*)ws;                                        // 8 KB
    int*   nbr  = (int*)(ws + 8192);                               // 512 KB
    float* gef  = (float*)(ws + 8192 + (size_t)ROWS * MAXD * 4);   // 8 MB
    float* h    = gef + (size_t)ROWS * MAXD * EE;
    float* hnA  = h   + (size_t)ROWS * FF;
    float* hnB  = hnA + (size_t)ROWS * MM;

    // launch 1: prep (dense scan + compaction + hn0; h0 not materialized)
    k_prep2<<<ROWS/2, 512, 0, stream>>>(nodes, edges, Wmsg, bmsg,
                                        deg, nbr, gef, hnA, out);
    // launch 2: pass 0  (h-state from nodes; hnA -> hnB)
    k_p12<<<ROWS/2, 512, 0, stream>>>(Wmsg, bmsg, Wi, Wh, bi, bh,
                                      nodes, Wg, bg, We, be, deg, nbr, gef,
                                      nodes, hnA, hnB, h, out, 0);
    // launch 3: pass 1  (h-state from h; hnB -> hnA)
    k_p12<<<ROWS/2, 512, 0, stream>>>(Wmsg, bmsg, Wi, Wh, bi, bh,
                                      nodes, Wg, bg, We, be, deg, nbr, gef,
                                      h, hnB, hnA, h, out, 0);
    // launch 4: pass 2 + readout (h-state from h)
    k_p12<<<ROWS/2, 512, 0, stream>>>(Wmsg, bmsg, Wi, Wh, bi, bh,
                                      nodes, Wg, bg, We, be, deg, nbr, gef,
                                      h, hnA, hnB, h, out, 1);
}